// Round 1
// baseline (1195.698 us; speedup 1.0000x reference)
//
#include <hip/hip_runtime.h>
#include <cstdint>
#include <cstddef>

// ---------------------------------------------------------------------------
// B_Conv2d_ConvNN_K_N: two ConvNN-branching layers + fc1 + fc2, fp32.
// Key structural facts used:
//  * pixel_shuffle(L1) o pixel_unshuffle(L2) == identity -> L2 consumes L1's
//    1x1-conv output (B,64,16,16) directly.
//  * L2's trailing pixel_shuffle is folded into the 1x1 conv store index.
//  * top-k ordering feeds order-dependent weights -> dist computed with
//    sequential ascending-c accumulation, fp contract OFF, stable tie-break
//    (smaller dist, then smaller sample index) to match lax.top_k / np.
// ---------------------------------------------------------------------------

#define DI static __device__ __forceinline__

// pixel_unshuffle(r=2) of x (B,3,32,32): xu[b][c][h][w] = x[b][c>>2][2h+((c>>1)&1)][2w+(c&1)]
DI float xu1_at(const float* __restrict__ x, int b, int c, int t) {
  int h = t >> 4, w = t & 15;
  return x[(((size_t)b * 3 + (c >> 2)) * 32 + 2 * h + ((c >> 1) & 1)) * 32 + 2 * w + (c & 1)];
}

// ---------------- conv3x3 (SAME), 16 out-channels per block ----------------
template <int CIN, bool GATHER, int CCTOT>
__global__ __launch_bounds__(256) void k_conv3x3(
    const float* __restrict__ xsrc,  // GATHER: original x (B,3,32,32)
    const float* __restrict__ xu,    // !GATHER: (B,CIN,256)
    const float* __restrict__ w,     // (OC_total, CIN, 3, 3)
    const float* __restrict__ bias,
    float* __restrict__ ycat)        // (B, CCTOT, 256), relu applied
{
  int b = blockIdx.x;
  int ocb = blockIdx.y * 16;
  __shared__ float xs[CIN * 256];
  int t = threadIdx.x;
  if (GATHER) {
    for (int i = t; i < CIN * 256; i += 256) {
      int c = i >> 8, tt = i & 255;
      xs[i] = xu1_at(xsrc, b, c, tt);
    }
  } else {
    for (int i = t; i < CIN * 256; i += 256) xs[i] = xu[(size_t)b * CIN * 256 + i];
  }
  __syncthreads();
  int h = t >> 4, wc = t & 15;
  float acc[16];
#pragma unroll
  for (int o = 0; o < 16; ++o) acc[o] = bias[ocb + o];
  bool vh0 = h > 0, vh2 = h < 15, vw0 = wc > 0, vw2 = wc < 15;
  bool vm[9] = {vh0 && vw0, vh0, vh0 && vw2, vw0, true, vw2, vh2 && vw0, vh2, vh2 && vw2};
  int tcl[9];
#pragma unroll
  for (int dh = 0; dh < 3; ++dh)
#pragma unroll
    for (int dw = 0; dw < 3; ++dw) {
      int off = (h + dh - 1) * 16 + (wc + dw - 1);
      off = off < 0 ? 0 : (off > 255 ? 255 : off);  // clamped safe addr; masked by vm
      tcl[dh * 3 + dw] = off;
    }
#pragma unroll 2
  for (int ic = 0; ic < CIN; ++ic) {
    float xv[9];
#pragma unroll
    for (int tp = 0; tp < 9; ++tp) {
      float v = xs[ic * 256 + tcl[tp]];
      xv[tp] = vm[tp] ? v : 0.f;
    }
#pragma unroll
    for (int o = 0; o < 16; ++o) {
      const float* wp = w + ((size_t)(ocb + o) * CIN + ic) * 9;
#pragma unroll
      for (int tp = 0; tp < 9; ++tp) acc[o] = fmaf(xv[tp], wp[tp], acc[o]);
    }
  }
#pragma unroll
  for (int o = 0; o < 16; ++o)
    ycat[((size_t)b * CCTOT + ocb + o) * 256 + t] = fmaxf(acc[o], 0.f);
}

// ---------------- kNN branch: dist -> top9 -> gather-einsum ----------------
template <int C, int O, bool GATHER, int CCTOT, int OCBASE>
__global__ __launch_bounds__(256) void k_branch(
    const float* __restrict__ xsrc,  // GATHER: original x
    const float* __restrict__ xu,    // !GATHER: (B,C,256)
    const int* __restrict__ idx,     // (64,)
    const float* __restrict__ wb,    // (O, C, 9)
    const float* __restrict__ bb,    // (O,)
    float* __restrict__ ycat)        // (B, CCTOT, 256), relu applied
{
  int b = blockIdx.x, t = threadIdx.x;
  __shared__ float samps[C * 64];
  __shared__ float snv[64];
  __shared__ int idxs[64];
  if (t < 64) idxs[t] = idx[t];
  __syncthreads();
  for (int i = t; i < C * 64; i += 256) {
    int c = i >> 6, n = i & 63;
    int p = idxs[n];
    samps[i] = GATHER ? xu1_at(xsrc, b, c, p) : xu[((size_t)b * C + c) * 256 + p];
  }
  float xcol[C];
#pragma unroll
  for (int c = 0; c < C; ++c)
    xcol[c] = GATHER ? xu1_at(xsrc, b, c, t) : xu[((size_t)b * C + c) * 256 + t];
  float xn;
  {
#pragma clang fp contract(off)
    xn = 0.f;
#pragma unroll
    for (int c = 0; c < C; ++c) xn += xcol[c] * xcol[c];
  }
  __syncthreads();
  if (t < 64) {
#pragma clang fp contract(off)
    float s = 0.f;
#pragma unroll
    for (int c = 0; c < C; ++c) {
      float v = samps[c * 64 + t];
      s += v * v;
    }
    snv[t] = s;
  }
  __syncthreads();

  float bd[9];
  int bn[9];
#pragma unroll
  for (int i = 0; i < 9; ++i) {
    bd[i] = __builtin_inff();
    bn[i] = 1 << 30;
  }
#pragma unroll 1
  for (int n = 0; n < 64; ++n) {
    // sample pointer is wave-uniform -> force SGPR so samp reads become s_loads
    int p = __builtin_amdgcn_readfirstlane(idxs[n]);
    float d;
    {
#pragma clang fp contract(off)
      float dot = 0.f;
#pragma unroll
      for (int c = 0; c < C; ++c) {
        float sv = GATHER ? xu1_at(xsrc, b, c, p) : xu[((size_t)b * C + c) * 256 + p];
        dot += xcol[c] * sv;
      }
      d = (xn + snv[n]) - 2.f * dot;
    }
    // stable sorted-insert (ascending dist, tie -> smaller n first)
    float dc = d;
    int nc = n;
#pragma unroll
    for (int i = 0; i < 9; ++i) {
      bool sw = (dc < bd[i]) || (dc == bd[i] && nc < bn[i]);
      float ob = bd[i];
      int on = bn[i];
      bd[i] = sw ? dc : ob;
      bn[i] = sw ? nc : on;
      dc = sw ? ob : dc;
      nc = sw ? on : nc;
    }
  }

  float acc[O];
#pragma unroll
  for (int o = 0; o < O; ++o) acc[o] = bb[o];
#pragma unroll
  for (int k = 0; k < 9; ++k) {
    int n = bn[k];
#pragma unroll 4
    for (int c = 0; c < C; ++c) {
      float sv = samps[c * 64 + n];
#pragma unroll
      for (int o = 0; o < O; ++o)
        acc[o] = fmaf(sv, wb[((size_t)o * C + c) * 9 + k], acc[o]);
    }
  }
#pragma unroll
  for (int o = 0; o < O; ++o)
    ycat[((size_t)b * CCTOT + OCBASE + o) * 256 + t] = fmaxf(acc[o], 0.f);
}

// ---------------- 1x1 conv; SHUF folds layer2's pixel_shuffle --------------
template <int CIN, int OCB, int OCTOT, bool SHUF>
__global__ __launch_bounds__(256) void k_conv1x1(
    const float* __restrict__ yin,  // (B, CIN, 256)
    const float* __restrict__ w,    // (OCTOT, CIN)
    const float* __restrict__ bias,
    float* __restrict__ out)
{
  int b = blockIdx.x, ocb = blockIdx.y * OCB, t = threadIdx.x;
  __shared__ float ys[CIN * 256];
  for (int i = t; i < CIN * 256; i += 256) ys[i] = yin[(size_t)b * CIN * 256 + i];
  __syncthreads();
  float acc[OCB];
#pragma unroll
  for (int o = 0; o < OCB; ++o) acc[o] = bias[ocb + o];
#pragma unroll 4
  for (int ic = 0; ic < CIN; ++ic) {
    float xv = ys[ic * 256 + t];
#pragma unroll
    for (int o = 0; o < OCB; ++o)
      acc[o] = fmaf(xv, w[(size_t)(ocb + o) * CIN + ic], acc[o]);
  }
  int h = t >> 4, wc = t & 15;
#pragma unroll
  for (int o = 0; o < OCB; ++o) {
    int og = ocb + o;
    if (SHUF) {
      // pixel_shuffle(r=2): flat = (og>>2)*1024 + (2h+((og>>1)&1))*32 + (2w+(og&1))
      int flat = (og >> 2) * 1024 + (2 * h + ((og >> 1) & 1)) * 32 + (2 * wc + (og & 1));
      out[(size_t)b * 32768 + flat] = acc[o];
    } else {
      out[((size_t)b * OCTOT + og) * 256 + t] = acc[o];
    }
  }
}

// ---------------- fc1: split-K fp32 GEMM, 128x128 tile, 8x8 microtile ------
__global__ __launch_bounds__(256) void k_fc1(const float* __restrict__ A,   // (256, 32768)
                                             const float* __restrict__ W,   // (1024, 32768)
                                             float* __restrict__ parts)     // (16, 256, 1024)
{
  constexpr int KTOT = 32768;
  constexpr int LDP = 132;  // 128 + 4 pad, keeps float4 rows 16B-aligned
  int tid = threadIdx.x;
  int nb = blockIdx.x, mb = blockIdx.y, sb = blockIdx.z;
  int m0 = mb * 128, n0 = nb * 128, k0 = sb * 2048;
  __shared__ float As[16 * LDP];
  __shared__ float Ws[16 * LDP];
  int r = tid >> 1;
  int hf = (tid & 1) * 8;
  int tx = tid & 15, ty = tid >> 4;
  float acc[64];
#pragma unroll
  for (int i = 0; i < 64; ++i) acc[i] = 0.f;
  const float* Ab = A + (size_t)(m0 + r) * KTOT + k0 + hf;
  const float* Wb = W + (size_t)(n0 + r) * KTOT + k0 + hf;
  for (int ks = 0; ks < 2048; ks += 16) {
    float4 a0 = *(const float4*)(Ab + ks);
    float4 a1 = *(const float4*)(Ab + ks + 4);
    float4 w0 = *(const float4*)(Wb + ks);
    float4 w1 = *(const float4*)(Wb + ks + 4);
    __syncthreads();
    As[(hf + 0) * LDP + r] = a0.x; As[(hf + 1) * LDP + r] = a0.y;
    As[(hf + 2) * LDP + r] = a0.z; As[(hf + 3) * LDP + r] = a0.w;
    As[(hf + 4) * LDP + r] = a1.x; As[(hf + 5) * LDP + r] = a1.y;
    As[(hf + 6) * LDP + r] = a1.z; As[(hf + 7) * LDP + r] = a1.w;
    Ws[(hf + 0) * LDP + r] = w0.x; Ws[(hf + 1) * LDP + r] = w0.y;
    Ws[(hf + 2) * LDP + r] = w0.z; Ws[(hf + 3) * LDP + r] = w0.w;
    Ws[(hf + 4) * LDP + r] = w1.x; Ws[(hf + 5) * LDP + r] = w1.y;
    Ws[(hf + 6) * LDP + r] = w1.z; Ws[(hf + 7) * LDP + r] = w1.w;
    __syncthreads();
#pragma unroll
    for (int kk = 0; kk < 16; ++kk) {
      const float4 av0 = *(const float4*)&As[kk * LDP + ty * 8];
      const float4 av1 = *(const float4*)&As[kk * LDP + ty * 8 + 4];
      const float4 wv0 = *(const float4*)&Ws[kk * LDP + tx * 8];
      const float4 wv1 = *(const float4*)&Ws[kk * LDP + tx * 8 + 4];
      float am[8] = {av0.x, av0.y, av0.z, av0.w, av1.x, av1.y, av1.z, av1.w};
      float wn[8] = {wv0.x, wv0.y, wv0.z, wv0.w, wv1.x, wv1.y, wv1.z, wv1.w};
#pragma unroll
      for (int i = 0; i < 8; ++i)
#pragma unroll
        for (int j = 0; j < 8; ++j)
          acc[i * 8 + j] = fmaf(am[i], wn[j], acc[i * 8 + j]);
    }
  }
  float* P = parts + (size_t)sb * 262144;
#pragma unroll
  for (int i = 0; i < 8; ++i) {
    float4 s0 = make_float4(acc[i * 8 + 0], acc[i * 8 + 1], acc[i * 8 + 2], acc[i * 8 + 3]);
    float4 s1 = make_float4(acc[i * 8 + 4], acc[i * 8 + 5], acc[i * 8 + 6], acc[i * 8 + 7]);
    *(float4*)&P[(size_t)(m0 + ty * 8 + i) * 1024 + n0 + tx * 8] = s0;
    *(float4*)&P[(size_t)(m0 + ty * 8 + i) * 1024 + n0 + tx * 8 + 4] = s1;
  }
}

__global__ __launch_bounds__(256) void k_fc1_reduce(const float* __restrict__ parts,
                                                    const float* __restrict__ bias,
                                                    float* __restrict__ h1) {
  int i = blockIdx.x * 256 + threadIdx.x;  // 262144 total
  float s = 0.f;
#pragma unroll
  for (int sb = 0; sb < 16; ++sb) s += parts[(size_t)sb * 262144 + i];
  h1[i] = fmaxf(s + bias[i & 1023], 0.f);
}

// ---------------- fc2 ------------------------------------------------------
__global__ __launch_bounds__(256) void k_fc2(const float* __restrict__ h1,   // (256,1024)
                                             const float* __restrict__ w,    // (10,1024)
                                             const float* __restrict__ bias, // (10,)
                                             float* __restrict__ out)        // (256,10)
{
  int m = blockIdx.x, tid = threadIdx.x;
  __shared__ float hs[1024];
  __shared__ float ps[256];
  for (int i = tid; i < 1024; i += 256) hs[i] = h1[(size_t)m * 1024 + i];
  __syncthreads();
  int n = tid >> 4, sl = tid & 15;
  float p = 0.f;
  if (n < 10) {
    const float* wr = w + (size_t)n * 1024 + sl * 64;
    const float* hr = hs + sl * 64;
#pragma unroll 8
    for (int j = 0; j < 64; ++j) p = fmaf(hr[j], wr[j], p);
  }
  ps[tid] = p;
  __syncthreads();
  if (sl == 0 && n < 10) {
    float s = 0.f;
#pragma unroll
    for (int q = 0; q < 16; ++q) s += ps[n * 16 + q];
    out[(size_t)m * 10 + n] = s + bias[n];
  }
}

// ---------------------------------------------------------------------------
extern "C" void kernel_launch(void* const* d_in, const int* in_sizes, int n_in,
                              void* d_out, int out_size, void* d_ws, size_t ws_size,
                              hipStream_t stream) {
  (void)in_sizes; (void)n_in; (void)out_size; (void)ws_size;
  const float* x    = (const float*)d_in[0];
  const int*   idx1 = (const int*)d_in[1];
  const int*   idx2 = (const int*)d_in[2];
  const float* w1a  = (const float*)d_in[3];
  const float* b1a  = (const float*)d_in[4];
  const float* w1b  = (const float*)d_in[5];
  const float* b1b  = (const float*)d_in[6];
  const float* w1p  = (const float*)d_in[7];
  const float* b1p  = (const float*)d_in[8];
  const float* w2a  = (const float*)d_in[9];
  const float* b2a  = (const float*)d_in[10];
  const float* w2b  = (const float*)d_in[11];
  const float* b2b  = (const float*)d_in[12];
  const float* w2p  = (const float*)d_in[13];
  const float* b2p  = (const float*)d_in[14];
  const float* fc1w = (const float*)d_in[15];
  const float* fc1b = (const float*)d_in[16];
  const float* fc2w = (const float*)d_in[17];
  const float* fc2b = (const float*)d_in[18];

  // ws layout (floats), liveness-aliased; needs 18,874,368 floats = 75.5 MB
  float* ws    = (float*)d_ws;
  float* ycat1 = ws + 0;          // (B,32,256)  live: L1
  float* xu2   = ws + 2097152;    // (B,64,256)  live: L1-1x1 .. L2 branch
  float* ycat2 = ws + 6291456;    // (B,64,256)  live: L2
  float* hshuf = ws + 10485760;   // (B,32768)   live: L2-1x1 .. fc1
  float* parts = ws + 0;          // (16,256,1024) aliases ycat1+xu2 (dead)
  float* h1    = ws + 4194304;    // (256,1024)    aliases xu2 tail (dead)
  float* out   = (float*)d_out;

  // ---- layer 1 ----
  k_conv3x3<12, true, 32><<<dim3(256, 1), 256, 0, stream>>>(x, nullptr, w1a, b1a, ycat1);
  k_branch<12, 16, true, 32, 16><<<256, 256, 0, stream>>>(x, nullptr, idx1, w1b, b1b, ycat1);
  k_conv1x1<32, 64, 64, false><<<dim3(256, 1), 256, 0, stream>>>(ycat1, w1p, b1p, xu2);
  // ---- layer 2 (shuffle∘unshuffle between layers == identity) ----
  k_conv3x3<64, false, 64><<<dim3(256, 2), 256, 0, stream>>>(nullptr, xu2, w2a, b2a, ycat2);
  k_branch<64, 32, false, 64, 32><<<256, 256, 0, stream>>>(nullptr, xu2, idx2, w2b, b2b, ycat2);
  k_conv1x1<64, 64, 128, true><<<dim3(256, 2), 256, 0, stream>>>(ycat2, w2p, b2p, hshuf);
  // ---- fc1 (split-K) + fc2 ----
  k_fc1<<<dim3(8, 2, 16), 256, 0, stream>>>(hshuf, fc1w, parts);
  k_fc1_reduce<<<1024, 256, 0, stream>>>(parts, fc1b, h1);
  k_fc2<<<256, 256, 0, stream>>>(h1, fc2w, fc2b, out);
}

// Round 2
// 885.112 us; speedup vs baseline: 1.3509x; 1.3509x over previous
//
#include <hip/hip_runtime.h>
#include <cstdint>
#include <cstddef>

// ---------------------------------------------------------------------------
// B_Conv2d_ConvNN_K_N: two ConvNN-branching layers + fc1 + fc2, fp32.
//  * pixel_shuffle(L1) o pixel_unshuffle(L2) == identity -> L2 consumes L1's
//    1x1-conv output directly; L2's pixel_shuffle folded into 1x1 store index.
//  * Branch split into k_nbr (dist+top9 from LDS, ILP-8) + k_einsum (wb in
//    LDS, O-split grid). Dist computed identically for every sample n so
//    duplicate-index samples tie bitwise; stable insert == lax.top_k order.
// ---------------------------------------------------------------------------

#define DI static __device__ __forceinline__

// pixel_unshuffle(r=2) of x (B,3,32,32)
DI float xu1_at(const float* __restrict__ x, int b, int c, int t) {
  int h = t >> 4, w = t & 15;
  return x[(((size_t)b * 3 + (c >> 2)) * 32 + 2 * h + ((c >> 1) & 1)) * 32 + 2 * w + (c & 1)];
}

// ---------------- conv3x3 (SAME), 16 out-channels per block ----------------
template <int CIN, bool GATHER, int CCTOT>
__global__ __launch_bounds__(256) void k_conv3x3(
    const float* __restrict__ xsrc, const float* __restrict__ xu,
    const float* __restrict__ w, const float* __restrict__ bias,
    float* __restrict__ ycat)
{
  int b = blockIdx.x;
  int ocb = blockIdx.y * 16;
  __shared__ float xs[CIN * 256];
  int t = threadIdx.x;
  if (GATHER) {
    for (int i = t; i < CIN * 256; i += 256) {
      int c = i >> 8, tt = i & 255;
      xs[i] = xu1_at(xsrc, b, c, tt);
    }
  } else {
    for (int i = t; i < CIN * 256; i += 256) xs[i] = xu[(size_t)b * CIN * 256 + i];
  }
  __syncthreads();
  int h = t >> 4, wc = t & 15;
  float acc[16];
#pragma unroll
  for (int o = 0; o < 16; ++o) acc[o] = bias[ocb + o];
  bool vh0 = h > 0, vh2 = h < 15, vw0 = wc > 0, vw2 = wc < 15;
  bool vm[9] = {vh0 && vw0, vh0, vh0 && vw2, vw0, true, vw2, vh2 && vw0, vh2, vh2 && vw2};
  int tcl[9];
#pragma unroll
  for (int dh = 0; dh < 3; ++dh)
#pragma unroll
    for (int dw = 0; dw < 3; ++dw) {
      int off = (h + dh - 1) * 16 + (wc + dw - 1);
      off = off < 0 ? 0 : (off > 255 ? 255 : off);
      tcl[dh * 3 + dw] = off;
    }
#pragma unroll 2
  for (int ic = 0; ic < CIN; ++ic) {
    float xv[9];
#pragma unroll
    for (int tp = 0; tp < 9; ++tp) {
      float v = xs[ic * 256 + tcl[tp]];
      xv[tp] = vm[tp] ? v : 0.f;
    }
#pragma unroll
    for (int o = 0; o < 16; ++o) {
      const float* wp = w + ((size_t)(ocb + o) * CIN + ic) * 9;
#pragma unroll
      for (int tp = 0; tp < 9; ++tp) acc[o] = fmaf(xv[tp], wp[tp], acc[o]);
    }
  }
#pragma unroll
  for (int o = 0; o < 16; ++o)
    ycat[((size_t)b * CCTOT + ocb + o) * 256 + t] = fmaxf(acc[o], 0.f);
}

// ---------------- kNN: dist + top-9 (all from LDS, ILP-8) ------------------
template <int C, bool GATHER>
__global__ __launch_bounds__(256) void k_nbr(
    const float* __restrict__ xsrc, const float* __restrict__ xu,
    const int* __restrict__ idx, int* __restrict__ nbr)  // (B,9,256)
{
  int b = blockIdx.x, t = threadIdx.x;
  __shared__ float samps[C * 64];
  __shared__ float snv[64];
  __shared__ int idxs[64];
  if (t < 64) idxs[t] = idx[t];
  __syncthreads();
  for (int i = t; i < C * 64; i += 256) {
    int c = i >> 6, n = i & 63;
    int p = idxs[n];
    samps[i] = GATHER ? xu1_at(xsrc, b, c, p) : xu[((size_t)b * C + c) * 256 + p];
  }
  float xcol[C];
#pragma unroll
  for (int c = 0; c < C; ++c)
    xcol[c] = GATHER ? xu1_at(xsrc, b, c, t) : xu[((size_t)b * C + c) * 256 + t];
  float xn;
  {
#pragma clang fp contract(off)
    xn = 0.f;
#pragma unroll
    for (int c = 0; c < C; ++c) xn += xcol[c] * xcol[c];
  }
  __syncthreads();
  if (t < 64) {
#pragma clang fp contract(off)
    float s = 0.f;
#pragma unroll
    for (int c = 0; c < C; ++c) { float v = samps[c * 64 + t]; s += v * v; }
    snv[t] = s;
  }
  __syncthreads();

  float bd[9];
  int bn[9];
#pragma unroll
  for (int i = 0; i < 9; ++i) { bd[i] = __builtin_inff(); bn[i] = 1 << 30; }

#pragma unroll 1
  for (int n0 = 0; n0 < 64; n0 += 8) {
    float dot[8];
#pragma unroll
    for (int j = 0; j < 8; ++j) dot[j] = 0.f;
#pragma unroll 4
    for (int c = 0; c < C; ++c) {
      float xv = xcol[c];
#pragma unroll
      for (int j = 0; j < 8; ++j) dot[j] = fmaf(xv, samps[c * 64 + n0 + j], dot[j]);
    }
#pragma unroll
    for (int j = 0; j < 8; ++j) {
      float dc = (xn + snv[n0 + j]) - 2.f * dot[j];
      int nc = n0 + j;
#pragma unroll
      for (int i = 0; i < 9; ++i) {
        bool sw = (dc < bd[i]) || (dc == bd[i] && nc < bn[i]);
        float ob = bd[i]; int on = bn[i];
        bd[i] = sw ? dc : ob; bn[i] = sw ? nc : on;
        dc = sw ? ob : dc;   nc = sw ? on : nc;
      }
    }
  }
#pragma unroll
  for (int k = 0; k < 9; ++k) nbr[((size_t)b * 9 + k) * 256 + t] = bn[k];
}

// ---------------- gather-einsum, OGRP out-channels per block ---------------
template <int C, int OGRP, int CCTOT, int OCBASE, bool GATHER>
__global__ __launch_bounds__(256) void k_einsum(
    const float* __restrict__ xsrc, const float* __restrict__ xu,
    const int* __restrict__ idx, const int* __restrict__ nbr,
    const float* __restrict__ wb,  // (O, C, 9)
    const float* __restrict__ bb,
    float* __restrict__ ycat)
{
  int b = blockIdx.x, og = blockIdx.y * OGRP, t = threadIdx.x;
  __shared__ float samps[C * 64];
  __shared__ float wbs[OGRP * C * 9];
  __shared__ int idxs[64];
  if (t < 64) idxs[t] = idx[t];
  __syncthreads();
  for (int i = t; i < C * 64; i += 256) {
    int c = i >> 6, n = i & 63;
    int p = idxs[n];
    samps[i] = GATHER ? xu1_at(xsrc, b, c, p) : xu[((size_t)b * C + c) * 256 + p];
  }
  for (int i = t; i < OGRP * C * 9; i += 256)
    wbs[i] = wb[(size_t)og * C * 9 + i];
  int bn[9];
#pragma unroll
  for (int k = 0; k < 9; ++k) bn[k] = nbr[((size_t)b * 9 + k) * 256 + t];
  __syncthreads();
  float acc[OGRP];
#pragma unroll
  for (int o = 0; o < OGRP; ++o) acc[o] = bb[og + o];
#pragma unroll
  for (int k = 0; k < 9; ++k) {
    int n = bn[k];
#pragma unroll 4
    for (int c = 0; c < C; ++c) {
      float sv = samps[c * 64 + n];
#pragma unroll
      for (int o = 0; o < OGRP; ++o)
        acc[o] = fmaf(sv, wbs[(o * C + c) * 9 + k], acc[o]);
    }
  }
#pragma unroll
  for (int o = 0; o < OGRP; ++o)
    ycat[((size_t)b * CCTOT + OCBASE + og + o) * 256 + t] = fmaxf(acc[o], 0.f);
}

// ---------------- 1x1 conv; SHUF folds layer2's pixel_shuffle --------------
template <int CIN, int OCB, int OCTOT, bool SHUF>
__global__ __launch_bounds__(256) void k_conv1x1(
    const float* __restrict__ yin, const float* __restrict__ w,
    const float* __restrict__ bias, float* __restrict__ out)
{
  int b = blockIdx.x, ocb = blockIdx.y * OCB, t = threadIdx.x;
  __shared__ float ys[CIN * 256];
  for (int i = t; i < CIN * 256; i += 256) ys[i] = yin[(size_t)b * CIN * 256 + i];
  __syncthreads();
  float acc[OCB];
#pragma unroll
  for (int o = 0; o < OCB; ++o) acc[o] = bias[ocb + o];
#pragma unroll 4
  for (int ic = 0; ic < CIN; ++ic) {
    float xv = ys[ic * 256 + t];
#pragma unroll
    for (int o = 0; o < OCB; ++o)
      acc[o] = fmaf(xv, w[(size_t)(ocb + o) * CIN + ic], acc[o]);
  }
  int h = t >> 4, wc = t & 15;
#pragma unroll
  for (int o = 0; o < OCB; ++o) {
    int og = ocb + o;
    if (SHUF) {
      int flat = (og >> 2) * 1024 + (2 * h + ((og >> 1) & 1)) * 32 + (2 * wc + (og & 1));
      out[(size_t)b * 32768 + flat] = acc[o];
    } else {
      out[((size_t)b * OCTOT + og) * 256 + t] = acc[o];
    }
  }
}

// ---------------- fc1: split-K fp32 GEMM, 128x128 tile, 8x8 microtile ------
__global__ __launch_bounds__(256) void k_fc1(const float* __restrict__ A,   // (256, 32768)
                                             const float* __restrict__ W,   // (1024, 32768)
                                             float* __restrict__ parts)     // (32, 256, 1024)
{
  constexpr int KTOT = 32768;
  constexpr int LDP = 132;
  int tid = threadIdx.x;
  int nb = blockIdx.x, mb = blockIdx.y, sb = blockIdx.z;
  int m0 = mb * 128, n0 = nb * 128, k0 = sb * 1024;
  __shared__ float As[16 * LDP];
  __shared__ float Ws[16 * LDP];
  int r = tid >> 1;
  int hf = (tid & 1) * 8;
  int tx = tid & 15, ty = tid >> 4;
  float acc[64];
#pragma unroll
  for (int i = 0; i < 64; ++i) acc[i] = 0.f;
  const float* Ab = A + (size_t)(m0 + r) * KTOT + k0 + hf;
  const float* Wb = W + (size_t)(n0 + r) * KTOT + k0 + hf;
  for (int ks = 0; ks < 1024; ks += 16) {
    float4 a0 = *(const float4*)(Ab + ks);
    float4 a1 = *(const float4*)(Ab + ks + 4);
    float4 w0 = *(const float4*)(Wb + ks);
    float4 w1 = *(const float4*)(Wb + ks + 4);
    __syncthreads();
    As[(hf + 0) * LDP + r] = a0.x; As[(hf + 1) * LDP + r] = a0.y;
    As[(hf + 2) * LDP + r] = a0.z; As[(hf + 3) * LDP + r] = a0.w;
    As[(hf + 4) * LDP + r] = a1.x; As[(hf + 5) * LDP + r] = a1.y;
    As[(hf + 6) * LDP + r] = a1.z; As[(hf + 7) * LDP + r] = a1.w;
    Ws[(hf + 0) * LDP + r] = w0.x; Ws[(hf + 1) * LDP + r] = w0.y;
    Ws[(hf + 2) * LDP + r] = w0.z; Ws[(hf + 3) * LDP + r] = w0.w;
    Ws[(hf + 4) * LDP + r] = w1.x; Ws[(hf + 5) * LDP + r] = w1.y;
    Ws[(hf + 6) * LDP + r] = w1.z; Ws[(hf + 7) * LDP + r] = w1.w;
    __syncthreads();
#pragma unroll
    for (int kk = 0; kk < 16; ++kk) {
      const float4 av0 = *(const float4*)&As[kk * LDP + ty * 8];
      const float4 av1 = *(const float4*)&As[kk * LDP + ty * 8 + 4];
      const float4 wv0 = *(const float4*)&Ws[kk * LDP + tx * 8];
      const float4 wv1 = *(const float4*)&Ws[kk * LDP + tx * 8 + 4];
      float am[8] = {av0.x, av0.y, av0.z, av0.w, av1.x, av1.y, av1.z, av1.w};
      float wn[8] = {wv0.x, wv0.y, wv0.z, wv0.w, wv1.x, wv1.y, wv1.z, wv1.w};
#pragma unroll
      for (int i = 0; i < 8; ++i)
#pragma unroll
        for (int j = 0; j < 8; ++j)
          acc[i * 8 + j] = fmaf(am[i], wn[j], acc[i * 8 + j]);
    }
  }
  float* P = parts + (size_t)sb * 262144;
#pragma unroll
  for (int i = 0; i < 8; ++i) {
    float4 s0 = make_float4(acc[i * 8 + 0], acc[i * 8 + 1], acc[i * 8 + 2], acc[i * 8 + 3]);
    float4 s1 = make_float4(acc[i * 8 + 4], acc[i * 8 + 5], acc[i * 8 + 6], acc[i * 8 + 7]);
    *(float4*)&P[(size_t)(m0 + ty * 8 + i) * 1024 + n0 + tx * 8] = s0;
    *(float4*)&P[(size_t)(m0 + ty * 8 + i) * 1024 + n0 + tx * 8 + 4] = s1;
  }
}

__global__ __launch_bounds__(256) void k_fc1_reduce(const float* __restrict__ parts,
                                                    const float* __restrict__ bias,
                                                    float* __restrict__ h1) {
  int i = blockIdx.x * 256 + threadIdx.x;  // 262144 total
  float s = 0.f;
#pragma unroll
  for (int sb = 0; sb < 32; ++sb) s += parts[(size_t)sb * 262144 + i];
  h1[i] = fmaxf(s + bias[i & 1023], 0.f);
}

// ---------------- fc2 ------------------------------------------------------
__global__ __launch_bounds__(256) void k_fc2(const float* __restrict__ h1,
                                             const float* __restrict__ w,
                                             const float* __restrict__ bias,
                                             float* __restrict__ out)
{
  int m = blockIdx.x, tid = threadIdx.x;
  __shared__ float hs[1024];
  __shared__ float ps[256];
  for (int i = tid; i < 1024; i += 256) hs[i] = h1[(size_t)m * 1024 + i];
  __syncthreads();
  int n = tid >> 4, sl = tid & 15;
  float p = 0.f;
  if (n < 10) {
    const float* wr = w + (size_t)n * 1024 + sl * 64;
    const float* hr = hs + sl * 64;
#pragma unroll 8
    for (int j = 0; j < 64; ++j) p = fmaf(hr[j], wr[j], p);
  }
  ps[tid] = p;
  __syncthreads();
  if (sl == 0 && n < 10) {
    float s = 0.f;
#pragma unroll
    for (int q = 0; q < 16; ++q) s += ps[n * 16 + q];
    out[(size_t)m * 10 + n] = s + bias[n];
  }
}

// ---------------------------------------------------------------------------
extern "C" void kernel_launch(void* const* d_in, const int* in_sizes, int n_in,
                              void* d_out, int out_size, void* d_ws, size_t ws_size,
                              hipStream_t stream) {
  (void)in_sizes; (void)n_in; (void)out_size; (void)ws_size;
  const float* x    = (const float*)d_in[0];
  const int*   idx1 = (const int*)d_in[1];
  const int*   idx2 = (const int*)d_in[2];
  const float* w1a  = (const float*)d_in[3];
  const float* b1a  = (const float*)d_in[4];
  const float* w1b  = (const float*)d_in[5];
  const float* b1b  = (const float*)d_in[6];
  const float* w1p  = (const float*)d_in[7];
  const float* b1p  = (const float*)d_in[8];
  const float* w2a  = (const float*)d_in[9];
  const float* b2a  = (const float*)d_in[10];
  const float* w2b  = (const float*)d_in[11];
  const float* b2b  = (const float*)d_in[12];
  const float* w2p  = (const float*)d_in[13];
  const float* b2p  = (const float*)d_in[14];
  const float* fc1w = (const float*)d_in[15];
  const float* fc1b = (const float*)d_in[16];
  const float* fc2w = (const float*)d_in[17];
  const float* fc2b = (const float*)d_in[18];

  // ws layout (floats), liveness-aliased; total 18,874,368 floats = 75.5 MB
  float* ws    = (float*)d_ws;
  float* ycat1 = ws + 0;          // (B,32,256)   live: L1
  float* xu2   = ws + 2097152;    // (B,64,256)   live: L1-1x1 .. L2 einsum
  float* ycat2 = ws + 6291456;    // (B,64,256)   live: L2
  float* hshuf = ws + 10485760;   // (B,32768)    live: L2-1x1 .. fc1
  int*   nbr   = (int*)(ws + 10485760);  // (B,9,256) live: nbr..einsum (per layer; dead before hshuf)
  float* parts = ws + 0;          // (32,256,1024) aliases ycat1/xu2/ycat2 (dead)
  float* h1    = ws + 8650752;    // (256,1024)    between parts-end and hshuf
  float* out   = (float*)d_out;

  // ---- layer 1 ----
  k_conv3x3<12, true, 32><<<dim3(256, 1), 256, 0, stream>>>(x, nullptr, w1a, b1a, ycat1);
  k_nbr<12, true><<<256, 256, 0, stream>>>(x, nullptr, idx1, nbr);
  k_einsum<12, 16, 32, 16, true><<<dim3(256, 1), 256, 0, stream>>>(x, nullptr, idx1, nbr, w1b, b1b, ycat1);
  k_conv1x1<32, 64, 64, false><<<dim3(256, 1), 256, 0, stream>>>(ycat1, w1p, b1p, xu2);
  // ---- layer 2 (shuffle∘unshuffle between layers == identity) ----
  k_conv3x3<64, false, 64><<<dim3(256, 2), 256, 0, stream>>>(nullptr, xu2, w2a, b2a, ycat2);
  k_nbr<64, false><<<256, 256, 0, stream>>>(nullptr, xu2, idx2, nbr);
  k_einsum<64, 16, 64, 32, false><<<dim3(256, 2), 256, 0, stream>>>(nullptr, xu2, idx2, nbr, w2b, b2b, ycat2);
  k_conv1x1<64, 64, 128, true><<<dim3(256, 2), 256, 0, stream>>>(ycat2, w2p, b2p, hshuf);
  // ---- fc1 (split-K 32) + fc2 ----
  k_fc1<<<dim3(8, 2, 32), 256, 0, stream>>>(hshuf, fc1w, parts);
  k_fc1_reduce<<<1024, 256, 0, stream>>>(parts, fc1b, h1);
  k_fc2<<<256, 256, 0, stream>>>(h1, fc2w, fc2b, out);
}

// Round 5
// 768.196 us; speedup vs baseline: 1.5565x; 1.1522x over previous
//
#include <hip/hip_runtime.h>
#include <cstdint>
#include <cstddef>

// ---------------------------------------------------------------------------
// B_Conv2d_ConvNN_K_N: two ConvNN-branching layers + fc1 + fc2.
//  * shuffle(L1) o unshuffle(L2) == identity; L2 shuffle folded into 1x1 store.
//  * kNN dist math bitwise-identical to round-2 (fmaf chain ascending c,
//    (xn+snv)-2*dot inside contract(off)); stable insert == lax.top_k order.
//  * fc1: bf16x6 split MFMA (3-way split a=ah+am+al; products hh,hm,mh,hl,mm,lh;
//    dropped terms ~2^-26 rel). Measured anchor: bf16x3 gave 5.06e-3 absmax;
//    per-term error ratio 2^-9 -> predicted ~1e-5 added here.
// ---------------------------------------------------------------------------

#define DI static __device__ __forceinline__

typedef __attribute__((ext_vector_type(8))) short short8;
typedef __attribute__((ext_vector_type(4))) float f32x4;

DI unsigned short f2bf(float v) {
  unsigned u = __builtin_bit_cast(unsigned, v);
  unsigned r = (u + 0x7FFFu + ((u >> 16) & 1u)) >> 16;
  return (unsigned short)r;
}
DI float bf2f(unsigned short h) {
  unsigned u = ((unsigned)h) << 16;
  return __builtin_bit_cast(float, u);
}

// pixel_unshuffle(r=2) of x (B,3,32,32)
DI float xu1_at(const float* __restrict__ x, int b, int c, int t) {
  int h = t >> 4, w = t & 15;
  return x[(((size_t)b * 3 + (c >> 2)) * 32 + 2 * h + ((c >> 1) & 1)) * 32 + 2 * w + (c & 1)];
}

// ---------------- conv3x3 (SAME), 16 out-channels per block ----------------
template <int CIN, bool GATHER, int CCTOT>
__global__ __launch_bounds__(256) void k_conv3x3(
    const float* __restrict__ xsrc, const float* __restrict__ xu,
    const float* __restrict__ w, const float* __restrict__ bias,
    float* __restrict__ ycat)
{
  int b = blockIdx.x;
  int ocb = blockIdx.y * 16;
  __shared__ float xs[CIN * 256];
  int t = threadIdx.x;
  if (GATHER) {
    for (int i = t; i < CIN * 256; i += 256) {
      int c = i >> 8, tt = i & 255;
      xs[i] = xu1_at(xsrc, b, c, tt);
    }
  } else {
    for (int i = t; i < CIN * 256; i += 256) xs[i] = xu[(size_t)b * CIN * 256 + i];
  }
  __syncthreads();
  int h = t >> 4, wc = t & 15;
  float acc[16];
#pragma unroll
  for (int o = 0; o < 16; ++o) acc[o] = bias[ocb + o];
  bool vh0 = h > 0, vh2 = h < 15, vw0 = wc > 0, vw2 = wc < 15;
  bool vm[9] = {vh0 && vw0, vh0, vh0 && vw2, vw0, true, vw2, vh2 && vw0, vh2, vh2 && vw2};
  int tcl[9];
#pragma unroll
  for (int dh = 0; dh < 3; ++dh)
#pragma unroll
    for (int dw = 0; dw < 3; ++dw) {
      int off = (h + dh - 1) * 16 + (wc + dw - 1);
      off = off < 0 ? 0 : (off > 255 ? 255 : off);
      tcl[dh * 3 + dw] = off;
    }
#pragma unroll 2
  for (int ic = 0; ic < CIN; ++ic) {
    float xv[9];
#pragma unroll
    for (int tp = 0; tp < 9; ++tp) {
      float v = xs[ic * 256 + tcl[tp]];
      xv[tp] = vm[tp] ? v : 0.f;
    }
#pragma unroll
    for (int o = 0; o < 16; ++o) {
      const float* wp = w + ((size_t)(ocb + o) * CIN + ic) * 9;
#pragma unroll
      for (int tp = 0; tp < 9; ++tp) acc[o] = fmaf(xv[tp], wp[tp], acc[o]);
    }
  }
#pragma unroll
  for (int o = 0; o < 16; ++o)
    ycat[((size_t)b * CCTOT + ocb + o) * 256 + t] = fmaxf(acc[o], 0.f);
}

// ---------------- weight transpose: wb (O,C,9) -> wT (9,C,O) ---------------
__global__ __launch_bounds__(256) void k_prepw(
    const float* __restrict__ w1b, float* __restrict__ wT1,   // (9,12,16)
    const float* __restrict__ w2b, float* __restrict__ wT2)   // (9,64,32)
{
  int t = threadIdx.x;
  for (int i = t; i < 9 * 12 * 16; i += 256) {
    int k = i / (12 * 16), r = i % (12 * 16), c = r >> 4, o = r & 15;
    wT1[i] = w1b[((size_t)o * 12 + c) * 9 + k];
  }
  for (int i = t; i < 9 * 64 * 32; i += 256) {
    int k = i / (64 * 32), r = i % (64 * 32), c = r >> 5, o = r & 31;
    wT2[i] = w2b[((size_t)o * 64 + c) * 9 + k];
  }
}

// ---------------- sample prep: samp_T (B,64,STR) n-major, samp_cn (B,C,64),
//                  snv (B,64) with contract-off ascending-c accumulation -----
template <int C, int STR, bool GATHER>
__global__ __launch_bounds__(64) void k_prep(
    const float* __restrict__ xsrc, const float* __restrict__ xu,
    const int* __restrict__ idx,
    float* __restrict__ sampT, float* __restrict__ samp_cn,
    float* __restrict__ snvg)
{
  int b = blockIdx.x, n = threadIdx.x;  // 64 threads
  int p = idx[n];
  float s;
  {
#pragma clang fp contract(off)
    s = 0.f;
    for (int c = 0; c < C; ++c) {
      float v = GATHER ? xu1_at(xsrc, b, c, p) : xu[((size_t)b * C + c) * 256 + p];
      sampT[((size_t)b * 64 + n) * STR + c] = v;
      samp_cn[((size_t)b * C + c) * 64 + n] = v;
      s += v * v;
    }
  }
  snvg[(size_t)b * 64 + n] = s;
}

// ---------------- kNN: dist + top-9; samples via wave-uniform s_loads ------
template <int C, int STR, bool GATHER>
__global__ __launch_bounds__(256) void k_nbr(
    const float* __restrict__ xsrc, const float* __restrict__ xu,
    const float* __restrict__ sampT, const float* __restrict__ snvg,
    int* __restrict__ nbr)  // (B,9,256)
{
  int b = blockIdx.x, t = threadIdx.x;
  float xcol[C];
#pragma unroll
  for (int c = 0; c < C; ++c)
    xcol[c] = GATHER ? xu1_at(xsrc, b, c, t) : xu[((size_t)b * C + c) * 256 + t];
  float xn;
  {
#pragma clang fp contract(off)
    xn = 0.f;
#pragma unroll
    for (int c = 0; c < C; ++c) xn += xcol[c] * xcol[c];
  }
  float bd[9];
  int bn[9];
#pragma unroll
  for (int i = 0; i < 9; ++i) { bd[i] = __builtin_inff(); bn[i] = 1 << 30; }

#pragma unroll 1
  for (int n = 0; n < 64; ++n) {
    const float* sp = sampT + ((size_t)b * 64 + n) * STR;  // wave-uniform -> s_loads
    float snvn = snvg[(size_t)b * 64 + n];
    float d;
    {
#pragma clang fp contract(off)
      float dot = 0.f;
#pragma unroll
      for (int c = 0; c < C; ++c) dot = fmaf(xcol[c], sp[c], dot);
      d = (xn + snvn) - 2.f * dot;  // mul-then-sub, matches numpy exactly
    }
    if (d < bd[8] || (d == bd[8] && n < bn[8])) {
      float dc = d;
      int nc = n;
#pragma unroll
      for (int i = 0; i < 9; ++i) {
        bool sw = (dc < bd[i]) || (dc == bd[i] && nc < bn[i]);
        float ob = bd[i]; int on = bn[i];
        bd[i] = sw ? dc : ob; bn[i] = sw ? nc : on;
        dc = sw ? ob : dc;   nc = sw ? on : nc;
      }
    }
  }
#pragma unroll
  for (int k = 0; k < 9; ++k) nbr[((size_t)b * 9 + k) * 256 + t] = bn[k];
}

// ---------------- gather-einsum: weights via s_loads (wT), samples in LDS --
template <int C, int OGRP, int OTOT, int CCTOT, int OCBASE>
__global__ __launch_bounds__(256) void k_einsum(
    const float* __restrict__ samp_cn,  // (B,C,64)
    const int* __restrict__ nbr,
    const float* __restrict__ wT,       // (9,C,OTOT)
    const float* __restrict__ bb,
    float* __restrict__ ycat)
{
  int b = blockIdx.x, og = blockIdx.y * OGRP, t = threadIdx.x;
  __shared__ float samps[C * 64];
  for (int i = t; i < C * 64; i += 256)
    samps[i] = samp_cn[(size_t)b * C * 64 + i];  // contiguous, coalesced
  int bn[9];
#pragma unroll
  for (int k = 0; k < 9; ++k) bn[k] = nbr[((size_t)b * 9 + k) * 256 + t];
  __syncthreads();
  float acc[OGRP];
#pragma unroll
  for (int o = 0; o < OGRP; ++o) acc[o] = bb[og + o];
#pragma unroll 1
  for (int k = 0; k < 9; ++k) {
    int n = bn[k];
    const float* wp = wT + (size_t)k * C * OTOT + og;  // wave-uniform -> s_loads
#pragma unroll 4
    for (int c = 0; c < C; ++c) {
      float sv = samps[c * 64 + n];
#pragma unroll
      for (int o = 0; o < OGRP; ++o)
        acc[o] = fmaf(sv, wp[c * OTOT + o], acc[o]);
    }
  }
#pragma unroll
  for (int o = 0; o < OGRP; ++o)
    ycat[((size_t)b * CCTOT + OCBASE + og + o) * 256 + t] = fmaxf(acc[o], 0.f);
}

// ---------------- 1x1 conv; SHUF folds layer2's pixel_shuffle --------------
template <int CIN, int OCB, int OCTOT, bool SHUF>
__global__ __launch_bounds__(256) void k_conv1x1(
    const float* __restrict__ yin, const float* __restrict__ w,
    const float* __restrict__ bias, float* __restrict__ out)
{
  int b = blockIdx.x, ocb = blockIdx.y * OCB, t = threadIdx.x;
  __shared__ float ys[CIN * 256];
  for (int i = t; i < CIN * 256; i += 256) ys[i] = yin[(size_t)b * CIN * 256 + i];
  __syncthreads();
  float acc[OCB];
#pragma unroll
  for (int o = 0; o < OCB; ++o) acc[o] = bias[ocb + o];
#pragma unroll 4
  for (int ic = 0; ic < CIN; ++ic) {
    float xv = ys[ic * 256 + t];
#pragma unroll
    for (int o = 0; o < OCB; ++o)
      acc[o] = fmaf(xv, w[(size_t)(ocb + o) * CIN + ic], acc[o]);
  }
  int h = t >> 4, wc = t & 15;
#pragma unroll
  for (int o = 0; o < OCB; ++o) {
    int og = ocb + o;
    if (SHUF) {
      int flat = (og >> 2) * 1024 + (2 * h + ((og >> 1) & 1)) * 32 + (2 * wc + (og & 1));
      out[(size_t)b * 32768 + flat] = acc[o];
    } else {
      out[((size_t)b * OCTOT + og) * 256 + t] = acc[o];
    }
  }
}

// ---------------- fc1: bf16x6-split MFMA GEMM, 128x128 tile, BK=32 ---------
// C = A(256x32768) * W^T(32768x1024); split-K 32; parts (32,256,1024).
// a = ah+am+al (bf16 planes); keep products hh, hm, mh, hl, mm, lh.
__global__ __launch_bounds__(256, 2) void k_fc1(
    const float* __restrict__ A, const float* __restrict__ W,
    float* __restrict__ parts)
{
  constexpr int KTOT = 32768;
  constexpr int LDT = 40;  // 80 B rows: 16B-aligned, 20-bank stride (2-way free)
  __shared__ unsigned short Ah[128 * LDT], Am[128 * LDT], Al[128 * LDT];
  __shared__ unsigned short Wh[128 * LDT], Wm[128 * LDT], Wl[128 * LDT];
  int t = threadIdx.x;
  int nb = blockIdx.x, mb = blockIdx.y, sb = blockIdx.z;
  int m0 = mb * 128, n0 = nb * 128, k0 = sb * 1024;
  int wave = t >> 6, lane = t & 63;
  int q = lane >> 4, m16 = lane & 15;

  f32x4 acc[8][2];
#pragma unroll
  for (int mt = 0; mt < 8; ++mt)
#pragma unroll
    for (int nt = 0; nt < 2; ++nt) acc[mt][nt] = (f32x4){0.f, 0.f, 0.f, 0.f};

  int r8 = t >> 3, c4 = t & 7;  // staging: rows r8+32i, 16B col chunk c4

  for (int ks = 0; ks < 1024; ks += 32) {
    int kb = k0 + ks;
    float4 av[4], wv[4];
#pragma unroll
    for (int i = 0; i < 4; ++i) {
      av[i] = *(const float4*)(A + (size_t)(m0 + r8 + 32 * i) * KTOT + kb + c4 * 4);
      wv[i] = *(const float4*)(W + (size_t)(n0 + r8 + 32 * i) * KTOT + kb + c4 * 4);
    }
    __syncthreads();  // protect previous iteration's frag reads
#pragma unroll
    for (int i = 0; i < 4; ++i) {
      int off = (r8 + 32 * i) * LDT + c4 * 4;
      float vv[4] = {av[i].x, av[i].y, av[i].z, av[i].w};
      ushort4 h4, m4, l4;
      {
        float v = vv[0]; h4.x = f2bf(v); float r1 = v - bf2f(h4.x);
        m4.x = f2bf(r1); l4.x = f2bf(r1 - bf2f(m4.x));
      }
      {
        float v = vv[1]; h4.y = f2bf(v); float r1 = v - bf2f(h4.y);
        m4.y = f2bf(r1); l4.y = f2bf(r1 - bf2f(m4.y));
      }
      {
        float v = vv[2]; h4.z = f2bf(v); float r1 = v - bf2f(h4.z);
        m4.z = f2bf(r1); l4.z = f2bf(r1 - bf2f(m4.z));
      }
      {
        float v = vv[3]; h4.w = f2bf(v); float r1 = v - bf2f(h4.w);
        m4.w = f2bf(r1); l4.w = f2bf(r1 - bf2f(m4.w));
      }
      *(ushort4*)&Ah[off] = h4; *(ushort4*)&Am[off] = m4; *(ushort4*)&Al[off] = l4;
      float uu[4] = {wv[i].x, wv[i].y, wv[i].z, wv[i].w};
      {
        float v = uu[0]; h4.x = f2bf(v); float r1 = v - bf2f(h4.x);
        m4.x = f2bf(r1); l4.x = f2bf(r1 - bf2f(m4.x));
      }
      {
        float v = uu[1]; h4.y = f2bf(v); float r1 = v - bf2f(h4.y);
        m4.y = f2bf(r1); l4.y = f2bf(r1 - bf2f(m4.y));
      }
      {
        float v = uu[2]; h4.z = f2bf(v); float r1 = v - bf2f(h4.z);
        m4.z = f2bf(r1); l4.z = f2bf(r1 - bf2f(m4.z));
      }
      {
        float v = uu[3]; h4.w = f2bf(v); float r1 = v - bf2f(h4.w);
        m4.w = f2bf(r1); l4.w = f2bf(r1 - bf2f(m4.w));
      }
      *(ushort4*)&Wh[off] = h4; *(ushort4*)&Wm[off] = m4; *(ushort4*)&Wl[off] = l4;
    }
    __syncthreads();
    // -------- MFMA: 6 products per (mt,nt), ascending magnitude --------
    short8 bh[2], bm[2], bl[2];
#pragma unroll
    for (int nt = 0; nt < 2; ++nt) {
      int boff = (wave * 32 + nt * 16 + m16) * LDT + q * 8;
      bh[nt] = *(const short8*)&Wh[boff];
      bm[nt] = *(const short8*)&Wm[boff];
      bl[nt] = *(const short8*)&Wl[boff];
    }
#pragma unroll
    for (int mt = 0; mt < 8; ++mt) {
      int aoff = (mt * 16 + m16) * LDT + q * 8;
      short8 ah = *(const short8*)&Ah[aoff];
      short8 am = *(const short8*)&Am[aoff];
      short8 al = *(const short8*)&Al[aoff];
#pragma unroll
      for (int nt = 0; nt < 2; ++nt) {
        acc[mt][nt] = __builtin_amdgcn_mfma_f32_16x16x32_bf16(al, bh[nt], acc[mt][nt], 0, 0, 0);
        acc[mt][nt] = __builtin_amdgcn_mfma_f32_16x16x32_bf16(am, bm[nt], acc[mt][nt], 0, 0, 0);
        acc[mt][nt] = __builtin_amdgcn_mfma_f32_16x16x32_bf16(ah, bl[nt], acc[mt][nt], 0, 0, 0);
        acc[mt][nt] = __builtin_amdgcn_mfma_f32_16x16x32_bf16(am, bh[nt], acc[mt][nt], 0, 0, 0);
        acc[mt][nt] = __builtin_amdgcn_mfma_f32_16x16x32_bf16(ah, bm[nt], acc[mt][nt], 0, 0, 0);
        acc[mt][nt] = __builtin_amdgcn_mfma_f32_16x16x32_bf16(ah, bh[nt], acc[mt][nt], 0, 0, 0);
      }
    }
  }
  // -------- write partials: D row = q*4+reg, col = m16 (m89-verified) --------
  float* P = parts + (size_t)sb * 262144;
#pragma unroll
  for (int mt = 0; mt < 8; ++mt)
#pragma unroll
    for (int nt = 0; nt < 2; ++nt)
#pragma unroll
      for (int r2 = 0; r2 < 4; ++r2) {
        int m = m0 + mt * 16 + q * 4 + r2;
        int n = n0 + wave * 32 + nt * 16 + m16;
        P[(size_t)m * 1024 + n] = acc[mt][nt][r2];
      }
}

__global__ __launch_bounds__(256) void k_fc1_reduce(const float* __restrict__ parts,
                                                    const float* __restrict__ bias,
                                                    float* __restrict__ h1) {
  int i = blockIdx.x * 256 + threadIdx.x;  // 262144 total
  float s = 0.f;
#pragma unroll
  for (int sb = 0; sb < 32; ++sb) s += parts[(size_t)sb * 262144 + i];
  h1[i] = fmaxf(s + bias[i & 1023], 0.f);
}

// ---------------- fc2 ------------------------------------------------------
__global__ __launch_bounds__(256) void k_fc2(const float* __restrict__ h1,
                                             const float* __restrict__ w,
                                             const float* __restrict__ bias,
                                             float* __restrict__ out)
{
  int m = blockIdx.x, tid = threadIdx.x;
  __shared__ float hs[1024];
  __shared__ float ps[256];
  for (int i = tid; i < 1024; i += 256) hs[i] = h1[(size_t)m * 1024 + i];
  __syncthreads();
  int n = tid >> 4, sl = tid & 15;
  float p = 0.f;
  if (n < 10) {
    const float* wr = w + (size_t)n * 1024 + sl * 64;
    const float* hr = hs + sl * 64;
#pragma unroll 8
    for (int j = 0; j < 64; ++j) p = fmaf(hr[j], wr[j], p);
  }
  ps[tid] = p;
  __syncthreads();
  if (sl == 0 && n < 10) {
    float s = 0.f;
#pragma unroll
    for (int q = 0; q < 16; ++q) s += ps[n * 16 + q];
    out[(size_t)m * 10 + n] = s + bias[n];
  }
}

// ---------------------------------------------------------------------------
extern "C" void kernel_launch(void* const* d_in, const int* in_sizes, int n_in,
                              void* d_out, int out_size, void* d_ws, size_t ws_size,
                              hipStream_t stream) {
  (void)in_sizes; (void)n_in; (void)out_size; (void)ws_size;
  const float* x    = (const float*)d_in[0];
  const int*   idx1 = (const int*)d_in[1];
  const int*   idx2 = (const int*)d_in[2];
  const float* w1a  = (const float*)d_in[3];
  const float* b1a  = (const float*)d_in[4];
  const float* w1b  = (const float*)d_in[5];
  const float* b1b  = (const float*)d_in[6];
  const float* w1p  = (const float*)d_in[7];
  const float* b1p  = (const float*)d_in[8];
  const float* w2a  = (const float*)d_in[9];
  const float* b2a  = (const float*)d_in[10];
  const float* w2b  = (const float*)d_in[11];
  const float* b2b  = (const float*)d_in[12];
  const float* w2p  = (const float*)d_in[13];
  const float* b2p  = (const float*)d_in[14];
  const float* fc1w = (const float*)d_in[15];
  const float* fc1b = (const float*)d_in[16];
  const float* fc2w = (const float*)d_in[17];
  const float* fc2b = (const float*)d_in[18];

  // ws layout (floats); total 18,874,368 floats = 75.5 MB
  float* ws    = (float*)d_ws;
  float* ycat1 = ws + 0;          // (B,32,256)   live: L1
  float* xu2   = ws + 2097152;    // (B,64,256)   live: L1-1x1 .. L2 nbr/conv3x3
  float* ycat2 = ws + 6291456;    // (B,64,256)   live: L2
  float* hshuf = ws + 10485760;   // (B,32768)    live: L2-1x1 .. fc1
  // prep region aliases hshuf's slot (dead before conv1x1 L2 writes it):
  float* H       = ws + 10485760;
  int*   nbr     = (int*)(H + 0);        // (B,9,256) = 589,824
  float* sampT1  = H + 589824;           // (B,64,16) = 262,144
  float* snv1    = H + 851968;           // (B,64)    =  16,384
  float* wT1     = H + 868352;           // (9,12,16) =   1,728
  float* sampT2  = H + 870080;           // (B,64,64) = 1,048,576
  float* snv2    = H + 1918656;          // (B,64)    =  16,384
  float* wT2     = H + 1935040;          // (9,64,32) =  18,432
  float* samp_cn1 = H + 1953472;         // (B,12,64) = 196,608
  float* samp_cn2 = H + 2150080;         // (B,64,64) = 1,048,576
  float* parts = ws + 0;          // (32,256,1024) = 8,388,608; live only at fc1
  float* h1    = ws + 8650752;    // (256,1024); gap between parts-end and hshuf
  float* out   = (float*)d_out;

  // ---- prep ----
  k_prepw<<<1, 256, 0, stream>>>(w1b, wT1, w2b, wT2);
  // ---- layer 1 ----
  k_conv3x3<12, true, 32><<<dim3(256, 1), 256, 0, stream>>>(x, nullptr, w1a, b1a, ycat1);
  k_prep<12, 16, true><<<256, 64, 0, stream>>>(x, nullptr, idx1, sampT1, samp_cn1, snv1);
  k_nbr<12, 16, true><<<256, 256, 0, stream>>>(x, nullptr, sampT1, snv1, nbr);
  k_einsum<12, 16, 16, 32, 16><<<dim3(256, 1), 256, 0, stream>>>(samp_cn1, nbr, wT1, b1b, ycat1);
  k_conv1x1<32, 64, 64, false><<<dim3(256, 1), 256, 0, stream>>>(ycat1, w1p, b1p, xu2);
  // ---- layer 2 ----
  k_conv3x3<64, false, 64><<<dim3(256, 2), 256, 0, stream>>>(nullptr, xu2, w2a, b2a, ycat2);
  k_prep<64, 64, false><<<256, 64, 0, stream>>>(nullptr, xu2, idx2, sampT2, samp_cn2, snv2);
  k_nbr<64, 64, false><<<256, 256, 0, stream>>>(nullptr, xu2, sampT2, snv2, nbr);
  k_einsum<64, 16, 32, 64, 32><<<dim3(256, 2), 256, 0, stream>>>(samp_cn2, nbr, wT2, b2b, ycat2);
  k_conv1x1<64, 64, 128, true><<<dim3(256, 2), 256, 0, stream>>>(ycat2, w2p, b2p, hshuf);
  // ---- fc1 (bf16x6 MFMA, split-K 32) + fc2 ----
  k_fc1<<<dim3(8, 2, 32), 256, 0, stream>>>(hshuf, fc1w, parts);
  k_fc1_reduce<<<1024, 256, 0, stream>>>(parts, fc1b, h1);
  k_fc2<<<256, 256, 0, stream>>>(h1, fc2w, fc2b, out);
}

// Round 7
// 692.606 us; speedup vs baseline: 1.7264x; 1.1091x over previous
//
#include <hip/hip_runtime.h>
#include <cstdint>
#include <cstddef>

// ---------------------------------------------------------------------------
// B_Conv2d_ConvNN_K_N: two ConvNN-branching layers + fc1 + fc2.
//  * shuffle(L1) o unshuffle(L2) == identity; L2 shuffle folded into 1x1 store.
//  * kNN dist math bitwise-identical to round-2 (contract-off, ascending-c
//    fmaf chain, (xn+snv)-2*dot); stable insert == lax.top_k order.
//  * Weights pre-transposed o-contiguous -> float4 loads; weights live in a
//    DEDICATED ws region (round-6 bug: they aliased hshuf -> race w/ conv1x1).
//  * fc1: bf16x6-split MFMA; W frags direct global->reg (no LDS), A via LDS.
// ---------------------------------------------------------------------------

#define DI static __device__ __forceinline__

typedef __attribute__((ext_vector_type(8))) short short8;
typedef __attribute__((ext_vector_type(4))) float f32x4;

DI unsigned short f2bf(float v) {
  unsigned u = __builtin_bit_cast(unsigned, v);
  unsigned r = (u + 0x7FFFu + ((u >> 16) & 1u)) >> 16;
  return (unsigned short)r;
}
DI float bf2f(unsigned short h) {
  unsigned u = ((unsigned)h) << 16;
  return __builtin_bit_cast(float, u);
}

// pixel_unshuffle(r=2) of x (B,3,32,32)
DI float xu1_at(const float* __restrict__ x, int b, int c, int t) {
  int h = t >> 4, w = t & 15;
  return x[(((size_t)b * 3 + (c >> 2)) * 32 + 2 * h + ((c >> 1) & 1)) * 32 + 2 * w + (c & 1)];
}

// ---------------- weight transposes ----------------------------------------
// wT*: (9,C,O) for einsum; wp*T: (CIN,O) for 1x1; wa*T: (CIN,9,O) for 3x3
__global__ __launch_bounds__(256) void k_prepw(
    const float* __restrict__ w1b, float* __restrict__ wT1,    // (9,12,16)
    const float* __restrict__ w2b, float* __restrict__ wT2,    // (9,64,32)
    const float* __restrict__ w1p, float* __restrict__ wp1T,   // (32,64)
    const float* __restrict__ w2p, float* __restrict__ wp2T,   // (64,128)
    const float* __restrict__ w1a, float* __restrict__ wa1T,   // (12,9,16)
    const float* __restrict__ w2a, float* __restrict__ wa2T)   // (64,9,32)
{
  int i = blockIdx.x * 256 + threadIdx.x;
  if (i < 1728) {
    int k = i / 192, r = i % 192, c = r >> 4, o = r & 15;
    wT1[i] = w1b[((size_t)o * 12 + c) * 9 + k];
    return;
  }
  i -= 1728;
  if (i < 18432) {
    int k = i / 2048, r = i % 2048, c = r >> 5, o = r & 31;
    wT2[i] = w2b[((size_t)o * 64 + c) * 9 + k];
    return;
  }
  i -= 18432;
  if (i < 2048) { int ic = i >> 6, o = i & 63; wp1T[i] = w1p[(size_t)o * 32 + ic]; return; }
  i -= 2048;
  if (i < 8192) { int ic = i >> 7, o = i & 127; wp2T[i] = w2p[(size_t)o * 64 + ic]; return; }
  i -= 8192;
  if (i < 1728) {
    int o = i & 15, u = i >> 4, ic = u / 9, tp = u % 9;
    wa1T[i] = w1a[((size_t)o * 12 + ic) * 9 + tp];
    return;
  }
  i -= 1728;
  if (i < 18432) {
    int o = i & 31, u = i >> 5, ic = u / 9, tp = u % 9;
    wa2T[i] = w2a[((size_t)o * 64 + ic) * 9 + tp];
  }
}

// ---------------- conv3x3: 2t x 8o per thread, waT (CIN,9,OCT) -------------
template <int CIN, bool GATHER, int CCTOT, int OCT>
__global__ __launch_bounds__(256) void k_conv3x3(
    const float* __restrict__ xsrc, const float* __restrict__ xu,
    const float* __restrict__ waT, const float* __restrict__ bias,
    float* __restrict__ ycat)
{
  int b = blockIdx.x;
  int ocb = blockIdx.y * 16;
  __shared__ float xs[CIN * 256];
  int t = threadIdx.x;
  if (GATHER) {
    for (int i = t; i < CIN * 256; i += 256) {
      int c = i >> 8, tt = i & 255;
      xs[i] = xu1_at(xsrc, b, c, tt);
    }
  } else {
    for (int i = t; i < CIN * 256; i += 256) xs[i] = xu[(size_t)b * CIN * 256 + i];
  }
  __syncthreads();
  int tt = t & 127, og = t >> 7;
  int oc0 = ocb + og * 8;
  int h0 = tt >> 4, wc = tt & 15;  // t0 = tt (h0 in [0,8)), t1 = tt+128 (h0+8)
  float acc0[8], acc1[8];
#pragma unroll
  for (int o = 0; o < 8; ++o) { acc0[o] = bias[oc0 + o]; acc1[o] = acc0[o]; }
  bool vw0 = wc > 0, vw2 = wc < 15, vh0 = h0 > 0, vh7 = h0 < 7;
  bool m0v[9] = {vh0 && vw0, vh0, vh0 && vw2, vw0, true, vw2, vw0, true, vw2};
  bool m1v[9] = {vw0, true, vw2, vw0, true, vw2, vh7 && vw0, vh7, vh7 && vw2};
  int tc0[9], tc1[9];
#pragma unroll
  for (int dh = 0; dh < 3; ++dh)
#pragma unroll
    for (int dw = 0; dw < 3; ++dw) {
      int o0 = (h0 + dh - 1) * 16 + (wc + dw - 1);
      int o1 = (h0 + 8 + dh - 1) * 16 + (wc + dw - 1);
      tc0[dh * 3 + dw] = o0 < 0 ? 0 : (o0 > 255 ? 255 : o0);
      tc1[dh * 3 + dw] = o1 < 0 ? 0 : (o1 > 255 ? 255 : o1);
    }
#pragma unroll 2
  for (int ic = 0; ic < CIN; ++ic) {
    float xv0[9], xv1[9];
#pragma unroll
    for (int tp = 0; tp < 9; ++tp) {
      float v0 = xs[ic * 256 + tc0[tp]];
      float v1 = xs[ic * 256 + tc1[tp]];
      xv0[tp] = m0v[tp] ? v0 : 0.f;
      xv1[tp] = m1v[tp] ? v1 : 0.f;
    }
    // chain per o: (ic ascending, tp ascending) == previous rounds' order
#pragma unroll
    for (int tp = 0; tp < 9; ++tp) {
      const float* wp = waT + ((size_t)ic * 9 + tp) * OCT + oc0;
      float4 wA = *(const float4*)wp;
      float4 wB = *(const float4*)(wp + 4);
      float wv[8] = {wA.x, wA.y, wA.z, wA.w, wB.x, wB.y, wB.z, wB.w};
#pragma unroll
      for (int o = 0; o < 8; ++o) {
        acc0[o] = fmaf(xv0[tp], wv[o], acc0[o]);
        acc1[o] = fmaf(xv1[tp], wv[o], acc1[o]);
      }
    }
  }
#pragma unroll
  for (int o = 0; o < 8; ++o) {
    ycat[((size_t)b * CCTOT + oc0 + o) * 256 + tt] = fmaxf(acc0[o], 0.f);
    ycat[((size_t)b * CCTOT + oc0 + o) * 256 + tt + 128] = fmaxf(acc1[o], 0.f);
  }
}

// ---------------- sample prep (256 threads, LDS transpose) -----------------
template <int C, int STR, bool GATHER>
__global__ __launch_bounds__(256) void k_prep(
    const float* __restrict__ xsrc, const float* __restrict__ xu,
    const int* __restrict__ idx,
    float* __restrict__ sampT, float* __restrict__ samp_cn,
    float* __restrict__ snvg)
{
  int b = blockIdx.x, t = threadIdx.x;
  __shared__ float sph[C * 64];
  __shared__ int idxs[64];
  if (t < 64) idxs[t] = idx[t];
  __syncthreads();
  for (int i = t; i < C * 64; i += 256) {
    int c = i >> 6, n = i & 63;
    int p = idxs[n];
    sph[i] = GATHER ? xu1_at(xsrc, b, c, p) : xu[((size_t)b * C + c) * 256 + p];
  }
  __syncthreads();
  for (int i = t; i < C * 64; i += 256) samp_cn[(size_t)b * C * 64 + i] = sph[i];
  for (int i = t; i < 64 * STR; i += 256) {
    int n = i / STR, c = i % STR;
    if (c < C) sampT[(size_t)b * 64 * STR + i] = sph[c * 64 + n];
  }
  if (t < 64) {
    float s;
    {
#pragma clang fp contract(off)
      s = 0.f;
      for (int c = 0; c < C; ++c) { float v = sph[c * 64 + t]; s += v * v; }
    }
    snvg[(size_t)b * 64 + t] = s;
  }
}

// ---------------- kNN: dist + top-9; samples via wave-uniform loads --------
template <int C, int STR, bool GATHER>
__global__ __launch_bounds__(256) void k_nbr(
    const float* __restrict__ xsrc, const float* __restrict__ xu,
    const float* __restrict__ sampT, const float* __restrict__ snvg,
    int* __restrict__ nbr)  // (B,9,256)
{
  int b = blockIdx.x, t = threadIdx.x;
  float xcol[C];
#pragma unroll
  for (int c = 0; c < C; ++c)
    xcol[c] = GATHER ? xu1_at(xsrc, b, c, t) : xu[((size_t)b * C + c) * 256 + t];
  float xn;
  {
#pragma clang fp contract(off)
    xn = 0.f;
#pragma unroll
    for (int c = 0; c < C; ++c) xn += xcol[c] * xcol[c];
  }
  float bd[9];
  int bn[9];
#pragma unroll
  for (int i = 0; i < 9; ++i) { bd[i] = __builtin_inff(); bn[i] = 1 << 30; }

#pragma unroll 1
  for (int n = 0; n < 64; ++n) {
    const float* sp = sampT + ((size_t)b * 64 + n) * STR;  // wave-uniform
    float snvn = snvg[(size_t)b * 64 + n];
    float d;
    {
#pragma clang fp contract(off)
      float dot = 0.f;
#pragma unroll
      for (int c = 0; c < C; ++c) dot = fmaf(xcol[c], sp[c], dot);
      d = (xn + snvn) - 2.f * dot;
    }
    if (d < bd[8] || (d == bd[8] && n < bn[8])) {
      float dc = d;
      int nc = n;
#pragma unroll
      for (int i = 0; i < 9; ++i) {
        bool sw = (dc < bd[i]) || (dc == bd[i] && nc < bn[i]);
        float ob = bd[i]; int on = bn[i];
        bd[i] = sw ? dc : ob; bn[i] = sw ? nc : on;
        dc = sw ? ob : dc;   nc = sw ? on : nc;
      }
    }
  }
#pragma unroll
  for (int k = 0; k < 9; ++k) nbr[((size_t)b * 9 + k) * 256 + t] = bn[k];
}

// ---------------- gather-einsum: 2t x OPT o per thread ---------------------
template <int C, int OPT, int OTOT, int CCTOT, int OCBASE>
__global__ __launch_bounds__(256) void k_einsum(
    const float* __restrict__ samp_cn,  // (B,C,64)
    const int* __restrict__ nbr,
    const float* __restrict__ wT,       // (9,C,OTOT)
    const float* __restrict__ bb,
    float* __restrict__ ycat)
{
  int b = blockIdx.x, t = threadIdx.x;
  int tt = t & 127, og = t >> 7;
  int o0 = og * OPT;
  __shared__ float samps[C * 64];
  for (int i = t; i < C * 64; i += 256)
    samps[i] = samp_cn[(size_t)b * C * 64 + i];
  int bnA[9], bnB[9];
#pragma unroll
  for (int k = 0; k < 9; ++k) {
    bnA[k] = nbr[((size_t)b * 9 + k) * 256 + tt];
    bnB[k] = nbr[((size_t)b * 9 + k) * 256 + tt + 128];
  }
  __syncthreads();
  float acc0[OPT], acc1[OPT];
#pragma unroll
  for (int o = 0; o < OPT; ++o) { acc0[o] = bb[o0 + o]; acc1[o] = acc0[o]; }
#pragma unroll 1
  for (int k = 0; k < 9; ++k) {
    int n0 = bnA[k], n1 = bnB[k];
#pragma unroll 2
    for (int c = 0; c < C; ++c) {
      float sv0 = samps[c * 64 + n0];
      float sv1 = samps[c * 64 + n1];
      const float* wp = wT + ((size_t)k * C + c) * OTOT + o0;
#pragma unroll
      for (int oq = 0; oq < OPT / 4; ++oq) {
        float4 wv = ((const float4*)wp)[oq];
        float w4[4] = {wv.x, wv.y, wv.z, wv.w};
#pragma unroll
        for (int j = 0; j < 4; ++j) {
          acc0[oq * 4 + j] = fmaf(sv0, w4[j], acc0[oq * 4 + j]);
          acc1[oq * 4 + j] = fmaf(sv1, w4[j], acc1[oq * 4 + j]);
        }
      }
    }
  }
#pragma unroll
  for (int o = 0; o < OPT; ++o) {
    ycat[((size_t)b * CCTOT + OCBASE + o0 + o) * 256 + tt] = fmaxf(acc0[o], 0.f);
    ycat[((size_t)b * CCTOT + OCBASE + o0 + o) * 256 + tt + 128] = fmaxf(acc1[o], 0.f);
  }
}

// ---------------- 1x1 conv: 2t x OPT o, wpT (CIN,OCTOT); SHUF folds shuffle
template <int CIN, int OPT, int OCTOT, bool SHUF>
__global__ __launch_bounds__(256) void k_conv1x1(
    const float* __restrict__ yin, const float* __restrict__ wpT,
    const float* __restrict__ bias, float* __restrict__ out)
{
  int b = blockIdx.x, ocb = blockIdx.y * 2 * OPT, t = threadIdx.x;
  int tt = t & 127, og = t >> 7;
  int o0 = ocb + og * OPT;
  __shared__ float ys[CIN * 256];
  for (int i = t; i < CIN * 256; i += 256) ys[i] = yin[(size_t)b * CIN * 256 + i];
  __syncthreads();
  float acc0[OPT], acc1[OPT];
#pragma unroll
  for (int o = 0; o < OPT; ++o) { acc0[o] = bias[o0 + o]; acc1[o] = acc0[o]; }
#pragma unroll 2
  for (int ic = 0; ic < CIN; ++ic) {
    float sv0 = ys[ic * 256 + tt];
    float sv1 = ys[ic * 256 + tt + 128];
    const float* wp = wpT + (size_t)ic * OCTOT + o0;
#pragma unroll
    for (int oq = 0; oq < OPT / 4; ++oq) {
      float4 wv = ((const float4*)wp)[oq];
      float w4[4] = {wv.x, wv.y, wv.z, wv.w};
#pragma unroll
      for (int j = 0; j < 4; ++j) {
        acc0[oq * 4 + j] = fmaf(sv0, w4[j], acc0[oq * 4 + j]);
        acc1[oq * 4 + j] = fmaf(sv1, w4[j], acc1[oq * 4 + j]);
      }
    }
  }
  int h0 = tt >> 4, wc = tt & 15;
#pragma unroll
  for (int o = 0; o < OPT; ++o) {
    int ogl = o0 + o;
    if (SHUF) {
      int f0 = (ogl >> 2) * 1024 + (2 * h0 + ((ogl >> 1) & 1)) * 32 + (2 * wc + (ogl & 1));
      int f1 = (ogl >> 2) * 1024 + (2 * (h0 + 8) + ((ogl >> 1) & 1)) * 32 + (2 * wc + (ogl & 1));
      out[(size_t)b * 32768 + f0] = acc0[o];
      out[(size_t)b * 32768 + f1] = acc1[o];
    } else {
      out[((size_t)b * OCTOT + ogl) * 256 + tt] = acc0[o];
      out[((size_t)b * OCTOT + ogl) * 256 + tt + 128] = acc1[o];
    }
  }
}

// ---------------- fc1: bf16x6 MFMA, M64xN128, W frags direct from global ---
// C = A(256x32768) * W^T(32768x1024); split-K 32; parts (32,256,1024).
__global__ __launch_bounds__(256, 3) void k_fc1(
    const float* __restrict__ A, const float* __restrict__ W,
    float* __restrict__ parts)
{
  constexpr int KTOT = 32768;
  constexpr int LDT = 40;
  __shared__ unsigned short Ah[64 * LDT], Am[64 * LDT], Al[64 * LDT];
  int t = threadIdx.x;
  int nb = blockIdx.x, mb = blockIdx.y, sb = blockIdx.z;
  int m0 = mb * 64, n0 = nb * 128, k0 = sb * 1024;
  int wave = t >> 6, lane = t & 63;
  int q = lane >> 4, m16 = lane & 15;

  f32x4 acc[4][2];
#pragma unroll
  for (int mt = 0; mt < 4; ++mt)
#pragma unroll
    for (int nt = 0; nt < 2; ++nt) acc[mt][nt] = (f32x4){0.f, 0.f, 0.f, 0.f};

  int r8 = t >> 3, c4 = t & 7;
  const float* A0 = A + (size_t)(m0 + r8) * KTOT + k0 + c4 * 4;
  const float* A1 = A + (size_t)(m0 + r8 + 32) * KTOT + k0 + c4 * 4;
  const float* W0 = W + (size_t)(n0 + wave * 32 + m16) * KTOT + k0 + q * 8;
  const float* W1 = W + (size_t)(n0 + wave * 32 + 16 + m16) * KTOT + k0 + q * 8;

  for (int ks = 0; ks < 1024; ks += 32) {
    float4 a0 = *(const float4*)(A0 + ks);
    float4 a1 = *(const float4*)(A1 + ks);
    float4 w0a = *(const float4*)(W0 + ks), w0b = *(const float4*)(W0 + ks + 4);
    float4 w1a = *(const float4*)(W1 + ks), w1b = *(const float4*)(W1 + ks + 4);
    __syncthreads();  // protect previous iteration's A-frag reads
    {
      float vv[8] = {a0.x, a0.y, a0.z, a0.w, a1.x, a1.y, a1.z, a1.w};
      int off0 = r8 * LDT + c4 * 4, off1 = (r8 + 32) * LDT + c4 * 4;
      ushort4 h4, m4, l4;
#pragma unroll
      for (int g = 0; g < 2; ++g) {
        {
          float v = vv[g * 4 + 0]; h4.x = f2bf(v); float r1 = v - bf2f(h4.x);
          m4.x = f2bf(r1); l4.x = f2bf(r1 - bf2f(m4.x));
        }
        {
          float v = vv[g * 4 + 1]; h4.y = f2bf(v); float r1 = v - bf2f(h4.y);
          m4.y = f2bf(r1); l4.y = f2bf(r1 - bf2f(m4.y));
        }
        {
          float v = vv[g * 4 + 2]; h4.z = f2bf(v); float r1 = v - bf2f(h4.z);
          m4.z = f2bf(r1); l4.z = f2bf(r1 - bf2f(m4.z));
        }
        {
          float v = vv[g * 4 + 3]; h4.w = f2bf(v); float r1 = v - bf2f(h4.w);
          m4.w = f2bf(r1); l4.w = f2bf(r1 - bf2f(m4.w));
        }
        int off = g == 0 ? off0 : off1;
        *(ushort4*)&Ah[off] = h4; *(ushort4*)&Am[off] = m4; *(ushort4*)&Al[off] = l4;
      }
    }
    __syncthreads();
    // W frags: convert in registers (no LDS)
    short8 bh[2], bm[2], bl[2];
    {
      float wf0[8] = {w0a.x, w0a.y, w0a.z, w0a.w, w0b.x, w0b.y, w0b.z, w0b.w};
      float wf1[8] = {w1a.x, w1a.y, w1a.z, w1a.w, w1b.x, w1b.y, w1b.z, w1b.w};
#pragma unroll
      for (int j = 0; j < 8; ++j) {
        unsigned short h = f2bf(wf0[j]); float r1 = wf0[j] - bf2f(h);
        unsigned short m = f2bf(r1);
        bh[0][j] = (short)h; bm[0][j] = (short)m; bl[0][j] = (short)f2bf(r1 - bf2f(m));
        h = f2bf(wf1[j]); r1 = wf1[j] - bf2f(h);
        m = f2bf(r1);
        bh[1][j] = (short)h; bm[1][j] = (short)m; bl[1][j] = (short)f2bf(r1 - bf2f(m));
      }
    }
#pragma unroll
    for (int mt = 0; mt < 4; ++mt) {
      int aoff = (mt * 16 + m16) * LDT + q * 8;
      short8 ah = *(const short8*)&Ah[aoff];
      short8 am = *(const short8*)&Am[aoff];
      short8 al = *(const short8*)&Al[aoff];
#pragma unroll
      for (int nt = 0; nt < 2; ++nt) {
        acc[mt][nt] = __builtin_amdgcn_mfma_f32_16x16x32_bf16(al, bh[nt], acc[mt][nt], 0, 0, 0);
        acc[mt][nt] = __builtin_amdgcn_mfma_f32_16x16x32_bf16(am, bm[nt], acc[mt][nt], 0, 0, 0);
        acc[mt][nt] = __builtin_amdgcn_mfma_f32_16x16x32_bf16(ah, bl[nt], acc[mt][nt], 0, 0, 0);
        acc[mt][nt] = __builtin_amdgcn_mfma_f32_16x16x32_bf16(am, bh[nt], acc[mt][nt], 0, 0, 0);
        acc[mt][nt] = __builtin_amdgcn_mfma_f32_16x16x32_bf16(ah, bm[nt], acc[mt][nt], 0, 0, 0);
        acc[mt][nt] = __builtin_amdgcn_mfma_f32_16x16x32_bf16(ah, bh[nt], acc[mt][nt], 0, 0, 0);
      }
    }
  }
  // D row = q*4+reg, col = m16 (m89-verified)
  float* P = parts + (size_t)sb * 262144;
#pragma unroll
  for (int mt = 0; mt < 4; ++mt)
#pragma unroll
    for (int nt = 0; nt < 2; ++nt)
#pragma unroll
      for (int r2 = 0; r2 < 4; ++r2) {
        int m = m0 + mt * 16 + q * 4 + r2;
        int n = n0 + wave * 32 + nt * 16 + m16;
        P[(size_t)m * 1024 + n] = acc[mt][nt][r2];
      }
}

__global__ __launch_bounds__(256) void k_fc1_reduce(const float* __restrict__ parts,
                                                    const float* __restrict__ bias,
                                                    float* __restrict__ h1) {
  int i = blockIdx.x * 256 + threadIdx.x;  // 262144 total
  float s = 0.f;
#pragma unroll
  for (int sb = 0; sb < 32; ++sb) s += parts[(size_t)sb * 262144 + i];
  h1[i] = fmaxf(s + bias[i & 1023], 0.f);
}

// ---------------- fc2 ------------------------------------------------------
__global__ __launch_bounds__(256) void k_fc2(const float* __restrict__ h1,
                                             const float* __restrict__ w,
                                             const float* __restrict__ bias,
                                             float* __restrict__ out)
{
  int m = blockIdx.x, tid = threadIdx.x;
  __shared__ float hs[1024];
  __shared__ float ps[256];
  for (int i = tid; i < 1024; i += 256) hs[i] = h1[(size_t)m * 1024 + i];
  __syncthreads();
  int n = tid >> 4, sl = tid & 15;
  float p = 0.f;
  if (n < 10) {
    const float* wr = w + (size_t)n * 1024 + sl * 64;
    const float* hr = hs + sl * 64;
#pragma unroll 8
    for (int j = 0; j < 64; ++j) p = fmaf(hr[j], wr[j], p);
  }
  ps[tid] = p;
  __syncthreads();
  if (sl == 0 && n < 10) {
    float s = 0.f;
#pragma unroll
    for (int q = 0; q < 16; ++q) s += ps[n * 16 + q];
    out[(size_t)m * 10 + n] = s + bias[n];
  }
}

// ---------------------------------------------------------------------------
extern "C" void kernel_launch(void* const* d_in, const int* in_sizes, int n_in,
                              void* d_out, int out_size, void* d_ws, size_t ws_size,
                              hipStream_t stream) {
  (void)in_sizes; (void)n_in; (void)out_size; (void)ws_size;
  const float* x    = (const float*)d_in[0];
  const int*   idx1 = (const int*)d_in[1];
  const int*   idx2 = (const int*)d_in[2];
  const float* w1a  = (const float*)d_in[3];
  const float* b1a  = (const float*)d_in[4];
  const float* w1b  = (const float*)d_in[5];
  const float* b1b  = (const float*)d_in[6];
  const float* w1p  = (const float*)d_in[7];
  const float* b1p  = (const float*)d_in[8];
  const float* w2a  = (const float*)d_in[9];
  const float* b2a  = (const float*)d_in[10];
  const float* w2b  = (const float*)d_in[11];
  const float* b2b  = (const float*)d_in[12];
  const float* w2p  = (const float*)d_in[13];
  const float* b2p  = (const float*)d_in[14];
  const float* fc1w = (const float*)d_in[15];
  const float* fc1b = (const float*)d_in[16];
  const float* fc2w = (const float*)d_in[17];
  const float* fc2b = (const float*)d_in[18];

  // ws layout (floats); total 18,874,368 = 75.5 MB. Liveness (race-checked):
  //  phase1(L1): xu2 W, ycat1 RW | phase2(L2): xu2 R, ycat2 RW, hshuf W
  //  phase3(fc): parts RW (0..8.39M), h1, hshuf R
  //  weights @8,388,608..8,439,168: written only by k_prepw, read through
  //  conv1x1 L2; overlaps NOTHING (ycat2 ends exactly at 8,388,608).
  float* ws    = (float*)d_ws;
  float* xu2   = ws + 0;          // (B,64,256) = 4,194,304
  float* ycat1 = ws + 4194304;    // (B,32,256) = 2,097,152; phase-1 only
  float* ycat2 = ws + 4194304;    // (B,64,256) = 4,194,304; aliases dead ycat1
  float* WGT   = ws + 8388608;    // 50,560 weights, dedicated
  float* wT1   = WGT + 0;         // (9,12,16) =  1,728
  float* wT2   = WGT + 1728;      // (9,64,32) = 18,432
  float* wp1T  = WGT + 20160;     // (32,64)   =  2,048
  float* wp2T  = WGT + 22208;     // (64,128)  =  8,192
  float* wa1T  = WGT + 30400;     // (12,9,16) =  1,728
  float* wa2T  = WGT + 32128;     // (64,9,32) = 18,432  (ends 8,439,168)
  float* h1    = ws + 8650752;    // (256,1024) = 262,144 (ends 8,912,896)
  float* hshuf = ws + 10485760;   // (B,32768) = 8,388,608 (ends 18,874,368)
  // prep arrays alias hshuf's slot (all dead before conv1x1 L2 writes it):
  float* H        = ws + 10485760;
  int*   nbr      = (int*)(H + 0);       // (B,9,256) = 589,824
  float* sampT1   = H + 589824;          // (B,64,16) = 262,144
  float* snv1     = H + 851968;          // (B,64)    =  16,384
  float* sampT2   = H + 868352;          // (B,64,64) = 1,048,576
  float* snv2     = H + 1916928;         // (B,64)    =  16,384
  float* samp_cn1 = H + 1933312;         // (B,12,64) = 196,608
  float* samp_cn2 = H + 2129920;         // (B,64,64) = 1,048,576 (ends 3,178,496)
  float* parts = ws + 0;          // (32,256,1024) = 8,388,608; phase-3 only
  float* out   = (float*)d_out;

  // ---- prep (50,560 elements) ----
  k_prepw<<<198, 256, 0, stream>>>(w1b, wT1, w2b, wT2, w1p, wp1T, w2p, wp2T, w1a, wa1T, w2a, wa2T);
  // ---- layer 1 ----
  k_conv3x3<12, true, 32, 16><<<dim3(256, 1), 256, 0, stream>>>(x, nullptr, wa1T, b1a, ycat1);
  k_prep<12, 16, true><<<256, 256, 0, stream>>>(x, nullptr, idx1, sampT1, samp_cn1, snv1);
  k_nbr<12, 16, true><<<256, 256, 0, stream>>>(x, nullptr, sampT1, snv1, nbr);
  k_einsum<12, 8, 16, 32, 16><<<256, 256, 0, stream>>>(samp_cn1, nbr, wT1, b1b, ycat1);
  k_conv1x1<32, 32, 64, false><<<dim3(256, 1), 256, 0, stream>>>(ycat1, wp1T, b1p, xu2);
  // ---- layer 2 ----
  k_conv3x3<64, false, 64, 32><<<dim3(256, 2), 256, 0, stream>>>(nullptr, xu2, wa2T, b2a, ycat2);
  k_prep<64, 64, false><<<256, 256, 0, stream>>>(nullptr, xu2, idx2, sampT2, samp_cn2, snv2);
  k_nbr<64, 64, false><<<256, 256, 0, stream>>>(nullptr, xu2, sampT2, snv2, nbr);
  k_einsum<64, 16, 32, 64, 32><<<256, 256, 0, stream>>>(samp_cn2, nbr, wT2, b2b, ycat2);
  k_conv1x1<64, 32, 128, true><<<dim3(256, 2), 256, 0, stream>>>(ycat2, wp2T, b2p, hshuf);
  // ---- fc1 (bf16x6 MFMA, M64 tiles, split-K 32) + fc2 ----
  k_fc1<<<dim3(8, 4, 32), 256, 0, stream>>>(hshuf, fc1w, parts);
  k_fc1_reduce<<<1024, 256, 0, stream>>>(parts, fc1b, h1);
  k_fc2<<<256, 256, 0, stream>>>(h1, fc2w, fc2b, out);
}